// Round 8
// baseline (1144.645 us; speedup 1.0000x reference)
//
#include <hip/hip_runtime.h>
#include <hip/hip_bf16.h>

#define NEG_SLOPE 0.2f

typedef __attribute__((ext_vector_type(8))) short bf16x8;
typedef __attribute__((ext_vector_type(4))) float f32x4;

__device__ __forceinline__ unsigned short bf16hi(float v) {
    __hip_bfloat16 h = __float2bfloat16(v);
    return *(unsigned short*)&h;
}
__device__ __forceinline__ float bf16tof(unsigned short u) {
    __hip_bfloat16 h = *(__hip_bfloat16*)&u;
    return __bfloat162float(h);
}

// ---------------------------------------------------------------------------
// CSR build
// ---------------------------------------------------------------------------
__global__ void hist_kernel(const int* __restrict__ dst, int* __restrict__ cnt, int E) {
    int e = blockIdx.x * 256 + threadIdx.x;
    if (e < E) atomicAdd(&cnt[dst[e]], 1);
}

__global__ void scan_s1(const int* __restrict__ cnt, int* __restrict__ excl,
                        int* __restrict__ totals, int N) {
    __shared__ int lds[256];
    int t = threadIdx.x;
    int i = blockIdx.x * 256 + t;
    int v = (i < N) ? cnt[i] : 0;
    lds[t] = v;
    __syncthreads();
    #pragma unroll
    for (int off = 1; off < 256; off <<= 1) {
        int add = (t >= off) ? lds[t - off] : 0;
        __syncthreads();
        lds[t] += add;
        __syncthreads();
    }
    if (i < N) excl[i] = lds[t] - v;
    if (t == 255) totals[blockIdx.x] = lds[255];
}

__global__ void scan_s2(int* __restrict__ totals, int nb) {
    __shared__ int lds[256];
    int t = threadIdx.x;
    int v = (t < nb) ? totals[t] : 0;
    lds[t] = v;
    __syncthreads();
    #pragma unroll
    for (int off = 1; off < 256; off <<= 1) {
        int add = (t >= off) ? lds[t - off] : 0;
        __syncthreads();
        lds[t] += add;
        __syncthreads();
    }
    if (t < nb) totals[t] = lds[t] - v;   // exclusive over block totals
}

__global__ void scan_s3(int* __restrict__ row_ptr, const int* __restrict__ totals,
                        int* __restrict__ cursor, int N, int E) {
    int i = blockIdx.x * 256 + threadIdx.x;
    if (i < N) {
        int v = row_ptr[i] + totals[blockIdx.x];
        row_ptr[i] = v;
        cursor[i] = v;
    }
    if (i == 0) row_ptr[N] = E;
}

__global__ void scatter_kernel(const int* __restrict__ src, const int* __restrict__ dst,
                               int* __restrict__ cursor, int* __restrict__ col_src,
                               int* __restrict__ col_dst, int* __restrict__ col_eid, int E) {
    int e = blockIdx.x * 256 + threadIdx.x;
    if (e < E) {
        int d = dst[e];
        int pos = atomicAdd(&cursor[d], 1);
        col_src[pos] = src[e];
        col_dst[pos] = d;
        col_eid[pos] = e;
    }
}

// ---------------------------------------------------------------------------
// Pack We (fp32 [32,256]) into MFMA A-fragment order, bf16 hi + lo parts.
// ---------------------------------------------------------------------------
__global__ void pack_we(const float* __restrict__ We0, const float* __restrict__ We1,
                        unsigned short* __restrict__ WeP) {
    int t = blockIdx.x * 256 + threadIdx.x;
    if (t >= 4096) return;
    int layer = t >> 11;
    int part  = (t >> 10) & 1;
    int tile  = (t >> 6) & 15;
    int lane  = t & 63;
    const float* We = layer ? We1 : We0;
    int ch = tile * 16 + (lane & 15);
    int kb = (lane >> 4) * 8;
    union { unsigned short u[8]; uint4 v; } out;
    #pragma unroll
    for (int j = 0; j < 8; ++j) {
        float w = We[(size_t)(kb + j) * 256 + ch];
        unsigned short hi = bf16hi(w);
        out.u[j] = part ? bf16hi(w - bf16tof(hi)) : hi;
    }
    *(uint4*)(WeP + (size_t)t * 8) = out.v;
}

// ---------------------------------------------------------------------------
// Pack W = [Wl | Wr] (fp32 [K,256] each) into MFMA B-frag order, hi+lo bf16.
// ---------------------------------------------------------------------------
__global__ void pack_w(const float* __restrict__ Wl, const float* __restrict__ Wr,
                       int KT, unsigned short* __restrict__ out) {
    int t = blockIdx.x * 256 + threadIdx.x;
    int per = KT * 2048;             // KT*32*64
    if (t >= 2 * per) return;
    int part = t / per;
    int rem  = t % per;
    int kt   = rem >> 11;
    int nt   = (rem >> 6) & 31;
    int lane = rem & 63;
    int n  = nt * 16 + (lane & 15);
    int kb = kt * 32 + ((lane >> 4) * 8);
    const float* W = (n < 256) ? (Wl + n) : (Wr + (n - 256));
    union { unsigned short u[8]; uint4 v; } o;
    #pragma unroll
    for (int j = 0; j < 8; ++j) {
        float w = W[(size_t)(kb + j) * 256];
        unsigned short hi = bf16hi(w);
        o.u[j] = part ? bf16hi(w - bf16tof(hi)) : hi;
    }
    *(uint4*)(out + (size_t)t * 8) = o.v;
}

// ---------------------------------------------------------------------------
// conv_a: fp32 A[M,K] -> bf16 hi/lo in FRAGMENT-TILE order.
// Tile = 16 rows x 32 cols; stored [tile][part][lane][8] shorts (1 KB/part)
// so gemm_split2 can global_load_lds it linearly (lane l -> 16 B at l*16).
// One wave per tile. tile index = mtg*KT + kt.
// ---------------------------------------------------------------------------
__global__ __launch_bounds__(256) void conv_a(
    const float* __restrict__ A, int K, int ntiles,
    unsigned short* __restrict__ Apk)
{
    int gw = (blockIdx.x * 256 + threadIdx.x) >> 6;
    int lane = threadIdx.x & 63;
    if (gw >= ntiles) return;
    int KT  = K >> 5;
    int mtg = gw / KT;
    int kt  = gw % KT;
    int r16 = lane & 15;
    int kg  = lane >> 4;
    const float* ap = A + (size_t)(mtg * 16 + r16) * K + kt * 32 + kg * 8;
    float4 v0 = *(const float4*)ap;
    float4 v1 = *(const float4*)(ap + 4);
    float vv[8] = {v0.x, v0.y, v0.z, v0.w, v1.x, v1.y, v1.z, v1.w};
    union { unsigned short u[8]; uint4 q; } hi, lo;
    #pragma unroll
    for (int j = 0; j < 8; ++j) {
        unsigned short h = bf16hi(vv[j]);
        hi.u[j] = h;
        lo.u[j] = bf16hi(vv[j] - bf16tof(h));
    }
    size_t tb = (size_t)gw * 1024;               // shorts
    *(uint4*)(Apk + tb + lane * 8)       = hi.q;
    *(uint4*)(Apk + tb + 512 + lane * 8) = lo.q;
}

// ---------------------------------------------------------------------------
// gemm_split2: same math as gemm_split but A staged via global_load_lds from
// pre-converted Apk (zero conversion VALU in the K-loop), plus XCD-grouped
// block swizzle (bijective, col-blocks of a row-panel adjacent -> same XCD L2
// caches the A-panel across its 4 column blocks).
// ---------------------------------------------------------------------------
__global__ __launch_bounds__(256) void gemm_split2(
    const unsigned short* __restrict__ Apk, int M, int K,
    const unsigned short* __restrict__ Bf,   // [2][KT][32][64][8]
    const float* __restrict__ bl, const float* __restrict__ br,
    float* __restrict__ C)
{
    __shared__ unsigned short Af[2][8][64][8];   // 16 KB
    const int tid  = threadIdx.x;
    const int lane = tid & 63;
    const int w    = tid >> 6;

    const int nwg = gridDim.x;
    const int q8 = nwg >> 3, r8 = nwg & 7;
    const int xcd = blockIdx.x & 7, idx = blockIdx.x >> 3;
    const int L = (xcd < r8) ? xcd * (q8 + 1) + idx
                             : r8 * (q8 + 1) + (xcd - r8) * q8 + idx;
    const int m0   = (L >> 2) * 128;
    const int n0   = (L & 3) * 128;
    const int KT   = K >> 5;
    const int ntg0 = n0 >> 4;
    const int mtg0 = m0 >> 4;

    f32x4 acc[2][8];
    #pragma unroll
    for (int i = 0; i < 2; ++i)
        #pragma unroll
        for (int j = 0; j < 8; ++j) acc[i][j] = (f32x4){0.f, 0.f, 0.f, 0.f};

    const size_t partStride = (size_t)KT * 32 * 512;   // shorts

    for (int kt = 0; kt < KT; ++kt) {
        // async stage: 16 tiles (8 mt x 2 parts), 4 issues per wave.
        // LDS dest wave-uniform; global src per-lane (pre-swizzled layout).
        #pragma unroll
        for (int ii = 0; ii < 4; ++ii) {
            int i = w * 4 + ii;
            int mt = i >> 1, part = i & 1;
            const unsigned short* g =
                Apk + ((size_t)((mtg0 + mt) * KT + kt) * 2 + part) * 512 + lane * 8;
            unsigned short* l = &Af[part][mt][0][0];
            __builtin_amdgcn_global_load_lds(
                (const __attribute__((address_space(1))) unsigned int*)g,
                (__attribute__((address_space(3))) unsigned int*)l, 16, 0, 0);
        }
        __syncthreads();

        bf16x8 ah0 = *(const bf16x8*)&Af[0][w * 2 + 0][lane][0];
        bf16x8 ah1 = *(const bf16x8*)&Af[0][w * 2 + 1][lane][0];
        bf16x8 al0 = *(const bf16x8*)&Af[1][w * 2 + 0][lane][0];
        bf16x8 al1 = *(const bf16x8*)&Af[1][w * 2 + 1][lane][0];

        const unsigned short* bbase =
            Bf + ((size_t)kt * 32 + ntg0) * 512 + (size_t)lane * 8;
        #pragma unroll
        for (int nt = 0; nt < 8; ++nt) {
            bf16x8 bh  = *(const bf16x8*)(bbase + (size_t)nt * 512);
            bf16x8 blv = *(const bf16x8*)(bbase + partStride + (size_t)nt * 512);
            acc[0][nt] = __builtin_amdgcn_mfma_f32_16x16x32_bf16(ah0, bh,  acc[0][nt], 0, 0, 0);
            acc[1][nt] = __builtin_amdgcn_mfma_f32_16x16x32_bf16(ah1, bh,  acc[1][nt], 0, 0, 0);
            acc[0][nt] = __builtin_amdgcn_mfma_f32_16x16x32_bf16(ah0, blv, acc[0][nt], 0, 0, 0);
            acc[1][nt] = __builtin_amdgcn_mfma_f32_16x16x32_bf16(ah1, blv, acc[1][nt], 0, 0, 0);
            acc[0][nt] = __builtin_amdgcn_mfma_f32_16x16x32_bf16(al0, bh,  acc[0][nt], 0, 0, 0);
            acc[1][nt] = __builtin_amdgcn_mfma_f32_16x16x32_bf16(al1, bh,  acc[1][nt], 0, 0, 0);
        }
        __syncthreads();
    }

    const int q  = lane >> 4;
    const int cl = lane & 15;
    #pragma unroll
    for (int mti = 0; mti < 2; ++mti) {
        int gmb = m0 + (w * 2 + mti) * 16 + q * 4;
        #pragma unroll
        for (int nt = 0; nt < 8; ++nt) {
            int col = n0 + nt * 16 + cl;
            float bia = (col < 256) ? bl[col] : br[col - 256];
            #pragma unroll
            for (int r = 0; r < 4; ++r) {
                int gm = gmb + r;
                if (gm < M) C[(size_t)gm * 512 + col] = acc[mti][nt][r] + bia;
            }
        }
    }
}

// ---------------------------------------------------------------------------
// gemm_split (fallback, r7 behavior): in-loop fp32->bf16 staging.
// ---------------------------------------------------------------------------
__global__ __launch_bounds__(256) void gemm_split(
    const float* __restrict__ A, int M, int K,
    const unsigned short* __restrict__ Bf,
    const float* __restrict__ bl, const float* __restrict__ br,
    float* __restrict__ C)
{
    __shared__ unsigned short Af[2][8][64][8];
    const int tid  = threadIdx.x;
    const int lane = tid & 63;
    const int w    = tid >> 6;
    const int m0   = blockIdx.x * 128;
    const int n0   = blockIdx.y * 128;
    const int KT   = K >> 5;
    const int ntg0 = n0 >> 4;

    f32x4 acc[2][8];
    #pragma unroll
    for (int i = 0; i < 2; ++i)
        #pragma unroll
        for (int j = 0; j < 8; ++j) acc[i][j] = (f32x4){0.f, 0.f, 0.f, 0.f};

    const size_t partStride = (size_t)KT * 32 * 512;

    for (int kt = 0; kt < KT; ++kt) {
        #pragma unroll
        for (int i = 0; i < 4; ++i) {
            int idx = tid * 4 + i;
            int r   = idx >> 3;
            int kl  = (idx & 7) * 4;
            int gm  = m0 + r;
            float4 v = make_float4(0.f, 0.f, 0.f, 0.f);
            if (gm < M) v = *(const float4*)(A + (size_t)gm * K + kt * 32 + kl);
            unsigned short h0 = bf16hi(v.x), h1 = bf16hi(v.y);
            unsigned short h2 = bf16hi(v.z), h3 = bf16hi(v.w);
            unsigned short l0 = bf16hi(v.x - bf16tof(h0));
            unsigned short l1 = bf16hi(v.y - bf16tof(h1));
            unsigned short l2 = bf16hi(v.z - bf16tof(h2));
            unsigned short l3 = bf16hi(v.w - bf16tof(h3));
            int mt = r >> 4;
            int la = (r & 15) | ((kl >> 3) << 4);
            int j0 = kl & 7;
            *(uint2*)&Af[0][mt][la][j0] =
                make_uint2((unsigned int)h0 | ((unsigned int)h1 << 16),
                           (unsigned int)h2 | ((unsigned int)h3 << 16));
            *(uint2*)&Af[1][mt][la][j0] =
                make_uint2((unsigned int)l0 | ((unsigned int)l1 << 16),
                           (unsigned int)l2 | ((unsigned int)l3 << 16));
        }
        __syncthreads();

        bf16x8 ah0 = *(const bf16x8*)&Af[0][w * 2 + 0][lane][0];
        bf16x8 ah1 = *(const bf16x8*)&Af[0][w * 2 + 1][lane][0];
        bf16x8 al0 = *(const bf16x8*)&Af[1][w * 2 + 0][lane][0];
        bf16x8 al1 = *(const bf16x8*)&Af[1][w * 2 + 1][lane][0];

        const unsigned short* bbase =
            Bf + ((size_t)kt * 32 + ntg0) * 512 + (size_t)lane * 8;
        #pragma unroll
        for (int nt = 0; nt < 8; ++nt) {
            bf16x8 bh  = *(const bf16x8*)(bbase + (size_t)nt * 512);
            bf16x8 blv = *(const bf16x8*)(bbase + partStride + (size_t)nt * 512);
            acc[0][nt] = __builtin_amdgcn_mfma_f32_16x16x32_bf16(ah0, bh,  acc[0][nt], 0, 0, 0);
            acc[1][nt] = __builtin_amdgcn_mfma_f32_16x16x32_bf16(ah1, bh,  acc[1][nt], 0, 0, 0);
            acc[0][nt] = __builtin_amdgcn_mfma_f32_16x16x32_bf16(ah0, blv, acc[0][nt], 0, 0, 0);
            acc[1][nt] = __builtin_amdgcn_mfma_f32_16x16x32_bf16(ah1, blv, acc[1][nt], 0, 0, 0);
            acc[0][nt] = __builtin_amdgcn_mfma_f32_16x16x32_bf16(al0, bh,  acc[0][nt], 0, 0, 0);
            acc[1][nt] = __builtin_amdgcn_mfma_f32_16x16x32_bf16(al1, bh,  acc[1][nt], 0, 0, 0);
        }
        __syncthreads();
    }

    const int q  = lane >> 4;
    const int cl = lane & 15;
    #pragma unroll
    for (int mti = 0; mti < 2; ++mti) {
        int gmb = m0 + (w * 2 + mti) * 16 + q * 4;
        #pragma unroll
        for (int nt = 0; nt < 8; ++nt) {
            int col = n0 + nt * 16 + cl;
            float bia = (col < 256) ? bl[col] : br[col - 256];
            #pragma unroll
            for (int r = 0; r < 4; ++r) {
                int gm = gmb + r;
                if (gm < M) C[(size_t)gm * 512 + col] = acc[mti][nt][r] + bia;
            }
        }
    }
}

// ---------------------------------------------------------------------------
// FUSED logit + aggregate (unchanged from r7 — at scatter-BW ceiling).
// ---------------------------------------------------------------------------
template<bool PROJ>
__global__ __launch_bounds__(256) void gat_fused_t(
    const float* __restrict__ xlxr,
    const float* __restrict__ edge_attr,
    const int* __restrict__ col_src,
    const int* __restrict__ col_dst,
    const int* __restrict__ col_eid,
    const int* __restrict__ row_ptr,
    const unsigned short* __restrict__ WePl,
    const float* __restrict__ att,
    const float* __restrict__ bias,
    float* __restrict__ nmr,
    const float* __restrict__ Wout,
    const float* __restrict__ bout,
    float* __restrict__ out,
    float* __restrict__ denomB,
    int E, int W)
{
    __shared__ unsigned short AhiS[16][64][8];
    __shared__ unsigned short AloS[16][64][8];
    const int tid = threadIdx.x;
    #pragma unroll
    for (int i = 0; i < 4; ++i) {
        int idx = tid * 4 + i;
        ((uint4*)&AhiS[0][0][0])[idx] = ((const uint4*)WePl)[idx];
        ((uint4*)&AloS[0][0][0])[idx] = ((const uint4*)(WePl + 8192))[idx];
    }
    __syncthreads();

    const int lane  = tid & 63;
    const int wid   = tid >> 6;
    const int q     = lane >> 4;
    const int e_sub = lane & 15;
    const int kb    = q * 8;
    const int ch4   = lane * 4;

    const int gw = blockIdx.x * 4 + wid;
    const int s_range = gw * W;
    if (s_range >= E) return;
    const int eEnd = min(E, s_range + W);

    const float4 bia4 = *(const float4*)(bias + ch4);
    float4 wo4 = make_float4(0.f, 0.f, 0.f, 0.f);
    if (PROJ) wo4 = *(const float4*)(Wout + ch4);

    int curDst = -1;
    float4 accB = make_float4(0.f, 0.f, 0.f, 0.f);
    float denB = 0.f;

    auto flush = [&]() {
        if (curDst >= 0) {
            int ra = row_ptr[curDst], rb = row_ptr[curDst + 1];
            bool comp = (ra % W != 0) && (rb % W != 0) && (ra / W == (rb - 1) / W);
            if (comp) {
                float inv = 1.0f / denB;
                float4 o;
                o.x = fmaxf(fmaf(accB.x, inv, bia4.x), 0.f);
                o.y = fmaxf(fmaf(accB.y, inv, bia4.y), 0.f);
                o.z = fmaxf(fmaf(accB.z, inv, bia4.z), 0.f);
                o.w = fmaxf(fmaf(accB.w, inv, bia4.w), 0.f);
                if (!PROJ) {
                    *(float4*)(nmr + (size_t)curDst * 256 + ch4) = o;
                } else {
                    float s = o.x * wo4.x;
                    s = fmaf(o.y, wo4.y, s);
                    s = fmaf(o.z, wo4.z, s);
                    s = fmaf(o.w, wo4.w, s);
                    #pragma unroll
                    for (int off = 32; off > 0; off >>= 1)
                        s += __shfl_xor(s, off, 64);
                    if (lane == 0) out[curDst] = s + bout[0];
                }
            } else {
                float* np = nmr + (size_t)curDst * 256 + ch4;
                atomicAdd(np + 0, accB.x);
                atomicAdd(np + 1, accB.y);
                atomicAdd(np + 2, accB.z);
                atomicAdd(np + 3, accB.w);
                if (e_sub == 0) atomicAdd(denomB + curDst * 4 + q, denB);
            }
            accB = make_float4(0.f, 0.f, 0.f, 0.f);
            denB = 0.f;
        }
    };

    for (int base = s_range; base < eEnd; base += 16) {
        const int cnt  = min(16, eEnd - base);
        const int slot = base + e_sub;
        const int sc   = min(slot, eEnd - 1);
        const int eid  = col_eid[sc];
        const int srcn = col_src[sc];
        const int dstn = col_dst[sc];

        const float* ap = edge_attr + (size_t)eid * 32 + kb;
        float4 v0 = *(const float4*)ap;
        float4 v1 = *(const float4*)(ap + 4);
        float vv[8] = {v0.x, v0.y, v0.z, v0.w, v1.x, v1.y, v1.z, v1.w};
        union { bf16x8 v; unsigned short u[8]; } bh, bl;
        #pragma unroll
        for (int i = 0; i < 8; ++i) {
            unsigned short hh = bf16hi(vv[i]);
            bh.u[i] = hh;
            bl.u[i] = bf16hi(vv[i] - bf16tof(hh));
        }

        const float* xlp = xlxr + (size_t)srcn * 512 + q * 4;
        const float* xrp = xlxr + (size_t)dstn * 512 + 256 + q * 4;

        float lph[4] = {0.f, 0.f, 0.f, 0.f};
        #pragma unroll
        for (int t = 0; t < 16; ++t) {
            bf16x8 ahi = *(const bf16x8*)&AhiS[t][lane][0];
            bf16x8 alo = *(const bf16x8*)&AloS[t][lane][0];
            f32x4 macc = {0.f, 0.f, 0.f, 0.f};
            macc = __builtin_amdgcn_mfma_f32_16x16x32_bf16(ahi, bh.v, macc, 0, 0, 0);
            macc = __builtin_amdgcn_mfma_f32_16x16x32_bf16(ahi, bl.v, macc, 0, 0, 0);
            macc = __builtin_amdgcn_mfma_f32_16x16x32_bf16(alo, bh.v, macc, 0, 0, 0);
            const float4 xl4 = *(const float4*)(xlp + t * 16);
            const float4 xr4 = *(const float4*)(xrp + t * 16);
            const float4 at4 = *(const float4*)(att + t * 16 + q * 4);
            float z0 = macc[0] + xl4.x + xr4.x; z0 = (z0 > 0.f) ? z0 : NEG_SLOPE * z0;
            float z1 = macc[1] + xl4.y + xr4.y; z1 = (z1 > 0.f) ? z1 : NEG_SLOPE * z1;
            float z2 = macc[2] + xl4.z + xr4.z; z2 = (z2 > 0.f) ? z2 : NEG_SLOPE * z2;
            float z3 = macc[3] + xl4.w + xr4.w; z3 = (z3 > 0.f) ? z3 : NEG_SLOPE * z3;
            float s = z0 * at4.x;
            s = fmaf(z1, at4.y, s);
            s = fmaf(z2, at4.z, s);
            s = fmaf(z3, at4.w, s);
            lph[t >> 2] += s;
        }
        #pragma unroll
        for (int hh = 0; hh < 4; ++hh) {
            lph[hh] += __shfl_xor(lph[hh], 16, 64);
            lph[hh] += __shfl_xor(lph[hh], 32, 64);
        }
        float lsel = (q == 0) ? lph[0] : (q == 1) ? lph[1] : (q == 2) ? lph[2] : lph[3];
        float psrc = __expf(lsel);

        auto phaseB = [&](int cnt2) {
            for (int eb = 0; eb < cnt2; eb += 4) {
                float pv[4]; int sv[4], dv[4];
                #pragma unroll
                for (int i = 0; i < 4; ++i) {
                    int e = eb + i;
                    int ec = (e < cnt2) ? e : cnt2 - 1;
                    pv[i] = __shfl(psrc, (lane & 48) | ec, 64);
                    if (e >= cnt2) pv[i] = 0.f;
                    sv[i] = __shfl(srcn, ec, 64);
                    dv[i] = __shfl(dstn, ec, 64);
                }
                float4 xv[4];
                #pragma unroll
                for (int i = 0; i < 4; ++i)
                    xv[i] = *(const float4*)(xlxr + (size_t)sv[i] * 512 + ch4);
                #pragma unroll
                for (int i = 0; i < 4; ++i) {
                    if (dv[i] != curDst) { flush(); curDst = dv[i]; }
                    denB += pv[i];
                    accB.x = fmaf(pv[i], xv[i].x, accB.x);
                    accB.y = fmaf(pv[i], xv[i].y, accB.y);
                    accB.z = fmaf(pv[i], xv[i].z, accB.z);
                    accB.w = fmaf(pv[i], xv[i].w, accB.w);
                }
            }
        };
        if (cnt == 16) phaseB(16); else phaseB(cnt);
    }
    flush();
}

// ---------------------------------------------------------------------------
// Finalize: boundary-run + deg-0 nodes (unchanged from r7).
// ---------------------------------------------------------------------------
template<bool PROJ>
__global__ __launch_bounds__(256) void finalize_t(
    const int* __restrict__ row_ptr,
    const float* __restrict__ denomB,
    const float* __restrict__ bias,
    float* __restrict__ nmr,
    const float* __restrict__ Wout, const float* __restrict__ bout,
    float* __restrict__ out, int N, int W)
{
    const int tid  = threadIdx.x;
    const int lane = tid & 63;
    const int wid  = tid >> 6;
    const int n = blockIdx.x * 4 + wid;
    if (n >= N) return;
    const int q   = lane >> 4;
    const int ch4 = lane * 4;

    const int a = row_ptr[n], b = row_ptr[n + 1];
    float4 o;
    if (a == b) {
        const float4 bia = *(const float4*)(bias + ch4);
        o.x = fmaxf(bia.x, 0.f);
        o.y = fmaxf(bia.y, 0.f);
        o.z = fmaxf(bia.z, 0.f);
        o.w = fmaxf(bia.w, 0.f);
    } else {
        bool comp = (a % W != 0) && (b % W != 0) && (a / W == (b - 1) / W);
        if (comp) return;
        const float4 nm = *(const float4*)(nmr + (size_t)n * 256 + ch4);
        const float inv = 1.0f / denomB[n * 4 + q];
        const float4 bia = *(const float4*)(bias + ch4);
        o.x = fmaxf(fmaf(nm.x, inv, bia.x), 0.f);
        o.y = fmaxf(fmaf(nm.y, inv, bia.y), 0.f);
        o.z = fmaxf(fmaf(nm.z, inv, bia.z), 0.f);
        o.w = fmaxf(fmaf(nm.w, inv, bia.w), 0.f);
    }
    if (!PROJ) {
        *(float4*)(nmr + (size_t)n * 256 + ch4) = o;
    } else {
        const float4 w4 = *(const float4*)(Wout + ch4);
        float s = o.x * w4.x;
        s = fmaf(o.y, w4.y, s);
        s = fmaf(o.z, w4.z, s);
        s = fmaf(o.w, w4.w, s);
        #pragma unroll
        for (int off = 32; off > 0; off >>= 1)
            s += __shfl_xor(s, off, 64);
        if (lane == 0) out[n] = s + bout[0];
    }
}

// ---------------------------------------------------------------------------
extern "C" void kernel_launch(void* const* d_in, const int* in_sizes, int n_in,
                              void* d_out, int out_size, void* d_ws, size_t ws_size,
                              hipStream_t stream) {
    const float* x         = (const float*)d_in[0];
    const int*   edge_idx  = (const int*)d_in[1];
    const float* edge_attr = (const float*)d_in[2];
    const float* W_l0 = (const float*)d_in[3];
    const float* b_l0 = (const float*)d_in[4];
    const float* W_r0 = (const float*)d_in[5];
    const float* b_r0 = (const float*)d_in[6];
    const float* W_e0 = (const float*)d_in[7];
    const float* att0 = (const float*)d_in[8];
    const float* bias0= (const float*)d_in[9];
    const float* W_l1 = (const float*)d_in[10];
    const float* b_l1 = (const float*)d_in[11];
    const float* W_r1 = (const float*)d_in[12];
    const float* b_r1 = (const float*)d_in[13];
    const float* W_e1 = (const float*)d_in[14];
    const float* att1 = (const float*)d_in[15];
    const float* bias1= (const float*)d_in[16];
    const float* W_out= (const float*)d_in[17];
    const float* b_out= (const float*)d_in[18];

    const int N = in_sizes[0] / 512;      // 50000
    const int E = in_sizes[1] / 2;        // 800000

    const int* src = edge_idx;
    const int* dst = edge_idx + E;

    // workspace layout
    char* ws = (char*)d_ws;
    size_t off = 0;
    float* bufA   = (float*)(ws + off); off += (size_t)N * 512 * 4;   // 102.4 MB
    float* bufB   = (float*)(ws + off); off += (size_t)N * 256 * 4;   //  51.2 MB
    float* denomB = (float*)(ws + off); off += (size_t)N * 4 * 4;     //   0.8 MB
    int* row_ptr  = (int*)(ws + off);   off += (((size_t)(N + 1) * 4 + 255) & ~(size_t)255);
    int* cursor   = (int*)(ws + off);   off += (((size_t)N * 4 + 255) & ~(size_t)255);
    int* col_src  = (int*)(ws + off);   off += (size_t)E * 4;
    int* col_dst  = (int*)(ws + off);   off += (size_t)E * 4;
    int* col_eid  = (int*)(ws + off);   off += (size_t)E * 4;
    int* totals   = (int*)(ws + off);   off += 1024;
    unsigned short* WeP = (unsigned short*)(ws + off); off += 4096 * 8 * 2;        // 64 KB
    unsigned short* Bf0 = (unsigned short*)(ws + off); off += (size_t)2 * 16 * 32 * 64 * 8 * 2; // 1 MB
    unsigned short* Bf1 = (unsigned short*)(ws + off); off += (size_t)2 * 8 * 32 * 64 * 8 * 2;  // 512 KB

    // Apk: shared region for pre-converted A (layer0: [M,512], layer1: [M,256])
    const int ntiles0 = (N >> 4) * 16;     // (M/16)*(512/32)
    const int ntiles1 = (N >> 4) * 8;      // (M/16)*(256/32)
    unsigned short* Apk = (unsigned short*)(ws + off);
    size_t apkBytes = (size_t)(ntiles0 > ntiles1 ? ntiles0 : ntiles1) * 2048 + 131072;
    off += apkBytes;
    const bool fast = (off <= ws_size) && ((N & 15) == 0);

    const int nbE = (E + 255) / 256;
    const int nbN = (N + 255) / 256;

    // ---- CSR build + weight prepack ----
    hipMemsetAsync(cursor, 0, (size_t)N * 4, stream);
    hist_kernel<<<nbE, 256, 0, stream>>>(dst, cursor, E);
    scan_s1<<<nbN, 256, 0, stream>>>(cursor, row_ptr, totals, N);
    scan_s2<<<1, 256, 0, stream>>>(totals, nbN);
    scan_s3<<<nbN, 256, 0, stream>>>(row_ptr, totals, cursor, N, E);
    scatter_kernel<<<nbE, 256, 0, stream>>>(src, dst, cursor, col_src, col_dst, col_eid, E);
    pack_we<<<16, 256, 0, stream>>>(W_e0, W_e1, WeP);
    pack_w<<<256, 256, 0, stream>>>(W_l0, W_r0, 16, Bf0);
    pack_w<<<128, 256, 0, stream>>>(W_l1, W_r1, 8, Bf1);

    const int nbx = (N + 127) / 128;
    dim3 ggrid(nbx, 4);

    // fused-kernel geometry
    const int NW  = 8192;
    const int nch = (E + 15) / 16;
    const int C   = (nch + NW - 1) / NW;
    const int W   = C * 16;
    const int nfin = (N + 3) / 4;

    // ---- Layer 0 ----
    if (fast) {
        conv_a<<<(ntiles0 + 3) / 4, 256, 0, stream>>>(x, 512, ntiles0, Apk);
        gemm_split2<<<nbx * 4, 256, 0, stream>>>(Apk, N, 512, Bf0, b_l0, b_r0, bufA);
    } else {
        gemm_split<<<ggrid, 256, 0, stream>>>(x, N, 512, Bf0, b_l0, b_r0, bufA);
    }
    hipMemsetAsync(bufB,   0, (size_t)N * 256 * 4, stream);
    hipMemsetAsync(denomB, 0, (size_t)N * 4 * 4,   stream);
    gat_fused_t<false><<<2048, 256, 0, stream>>>(
        bufA, edge_attr, col_src, col_dst, col_eid, row_ptr, WeP, att0, bias0,
        bufB, nullptr, nullptr, nullptr, denomB, E, W);
    finalize_t<false><<<nfin, 256, 0, stream>>>(
        row_ptr, denomB, bias0, bufB, nullptr, nullptr, nullptr, N, W);

    // ---- Layer 1 ----
    if (fast) {
        conv_a<<<(ntiles1 + 3) / 4, 256, 0, stream>>>(bufB, 256, ntiles1, Apk);
        gemm_split2<<<nbx * 4, 256, 0, stream>>>(Apk, N, 256, Bf1, b_l1, b_r1, bufA);
    } else {
        gemm_split<<<ggrid, 256, 0, stream>>>(bufB, N, 256, Bf1, b_l1, b_r1, bufA);
    }
    hipMemsetAsync(bufB,   0, (size_t)N * 256 * 4, stream);
    hipMemsetAsync(denomB, 0, (size_t)N * 4 * 4,   stream);
    gat_fused_t<true><<<2048, 256, 0, stream>>>(
        bufA, edge_attr, col_src, col_dst, col_eid, row_ptr, WeP + 16384, att1, bias1,
        bufB, W_out, b_out, (float*)d_out, denomB, E, W);
    finalize_t<true><<<nfin, 256, 0, stream>>>(
        row_ptr, denomB, bias1, bufB, W_out, b_out, (float*)d_out, N, W);
}

// Round 9
// 1074.161 us; speedup vs baseline: 1.0656x; 1.0656x over previous
//
#include <hip/hip_runtime.h>
#include <hip/hip_bf16.h>

#define NEG_SLOPE 0.2f

typedef __attribute__((ext_vector_type(8))) short bf16x8;
typedef __attribute__((ext_vector_type(4))) float f32x4;

__device__ __forceinline__ unsigned short bf16hi(float v) {
    __hip_bfloat16 h = __float2bfloat16(v);
    return *(unsigned short*)&h;
}
__device__ __forceinline__ float bf16tof(unsigned short u) {
    __hip_bfloat16 h = *(__hip_bfloat16*)&u;
    return __bfloat162float(h);
}

// ---------------------------------------------------------------------------
// CSR build
// ---------------------------------------------------------------------------
__global__ void hist_kernel(const int* __restrict__ dst, int* __restrict__ cnt, int E) {
    int e = blockIdx.x * 256 + threadIdx.x;
    if (e < E) atomicAdd(&cnt[dst[e]], 1);
}

__global__ void scan_s1(const int* __restrict__ cnt, int* __restrict__ excl,
                        int* __restrict__ totals, int N) {
    __shared__ int lds[256];
    int t = threadIdx.x;
    int i = blockIdx.x * 256 + t;
    int v = (i < N) ? cnt[i] : 0;
    lds[t] = v;
    __syncthreads();
    #pragma unroll
    for (int off = 1; off < 256; off <<= 1) {
        int add = (t >= off) ? lds[t - off] : 0;
        __syncthreads();
        lds[t] += add;
        __syncthreads();
    }
    if (i < N) excl[i] = lds[t] - v;
    if (t == 255) totals[blockIdx.x] = lds[255];
}

__global__ void scan_s2(int* __restrict__ totals, int nb) {
    __shared__ int lds[256];
    int t = threadIdx.x;
    int v = (t < nb) ? totals[t] : 0;
    lds[t] = v;
    __syncthreads();
    #pragma unroll
    for (int off = 1; off < 256; off <<= 1) {
        int add = (t >= off) ? lds[t - off] : 0;
        __syncthreads();
        lds[t] += add;
        __syncthreads();
    }
    if (t < nb) totals[t] = lds[t] - v;   // exclusive over block totals
}

__global__ void scan_s3(int* __restrict__ row_ptr, const int* __restrict__ totals,
                        int* __restrict__ cursor, int N, int E) {
    int i = blockIdx.x * 256 + threadIdx.x;
    if (i < N) {
        int v = row_ptr[i] + totals[blockIdx.x];
        row_ptr[i] = v;
        cursor[i] = v;
    }
    if (i == 0) row_ptr[N] = E;
}

__global__ void scatter_kernel(const int* __restrict__ src, const int* __restrict__ dst,
                               int* __restrict__ cursor, int* __restrict__ col_src,
                               int* __restrict__ col_dst, int* __restrict__ col_eid, int E) {
    int e = blockIdx.x * 256 + threadIdx.x;
    if (e < E) {
        int d = dst[e];
        int pos = atomicAdd(&cursor[d], 1);
        col_src[pos] = src[e];
        col_dst[pos] = d;
        col_eid[pos] = e;
    }
}

// ---------------------------------------------------------------------------
// Pack We (fp32 [32,256]) into MFMA A-fragment order, bf16 hi + lo parts.
// ---------------------------------------------------------------------------
__global__ void pack_we(const float* __restrict__ We0, const float* __restrict__ We1,
                        unsigned short* __restrict__ WeP) {
    int t = blockIdx.x * 256 + threadIdx.x;
    if (t >= 4096) return;
    int layer = t >> 11;
    int part  = (t >> 10) & 1;
    int tile  = (t >> 6) & 15;
    int lane  = t & 63;
    const float* We = layer ? We1 : We0;
    int ch = tile * 16 + (lane & 15);
    int kb = (lane >> 4) * 8;
    union { unsigned short u[8]; uint4 v; } out;
    #pragma unroll
    for (int j = 0; j < 8; ++j) {
        float w = We[(size_t)(kb + j) * 256 + ch];
        unsigned short hi = bf16hi(w);
        out.u[j] = part ? bf16hi(w - bf16tof(hi)) : hi;
    }
    *(uint4*)(WeP + (size_t)t * 8) = out.v;
}

// ---------------------------------------------------------------------------
// Pack W = [Wl | Wr] (fp32 [K,256] each) into MFMA B-frag order, hi+lo bf16.
// ---------------------------------------------------------------------------
__global__ void pack_w(const float* __restrict__ Wl, const float* __restrict__ Wr,
                       int KT, unsigned short* __restrict__ out) {
    int t = blockIdx.x * 256 + threadIdx.x;
    int per = KT * 2048;             // KT*32*64
    if (t >= 2 * per) return;
    int part = t / per;
    int rem  = t % per;
    int kt   = rem >> 11;
    int nt   = (rem >> 6) & 31;
    int lane = rem & 63;
    int n  = nt * 16 + (lane & 15);
    int kb = kt * 32 + ((lane >> 4) * 8);
    const float* W = (n < 256) ? (Wl + n) : (Wr + (n - 256));
    union { unsigned short u[8]; uint4 v; } o;
    #pragma unroll
    for (int j = 0; j < 8; ++j) {
        float w = W[(size_t)(kb + j) * 256];
        unsigned short hi = bf16hi(w);
        o.u[j] = part ? bf16hi(w - bf16tof(hi)) : hi;
    }
    *(uint4*)(out + (size_t)t * 8) = o.v;
}

// ---------------------------------------------------------------------------
// conv_a: fp32 A[M,K] -> bf16 hi/lo in FRAGMENT-TILE order.
// Tile = 16 rows x 32 cols; stored [tile][part][lane][8] shorts (1 KB/part)
// so gemm_split2 can global_load_lds it linearly. One wave per tile.
// ---------------------------------------------------------------------------
__global__ __launch_bounds__(256) void conv_a(
    const float* __restrict__ A, int K, int ntiles,
    unsigned short* __restrict__ Apk)
{
    int gw = (blockIdx.x * 256 + threadIdx.x) >> 6;
    int lane = threadIdx.x & 63;
    if (gw >= ntiles) return;
    int KT  = K >> 5;
    int mtg = gw / KT;
    int kt  = gw % KT;
    int r16 = lane & 15;
    int kg  = lane >> 4;
    const float* ap = A + (size_t)(mtg * 16 + r16) * K + kt * 32 + kg * 8;
    float4 v0 = *(const float4*)ap;
    float4 v1 = *(const float4*)(ap + 4);
    float vv[8] = {v0.x, v0.y, v0.z, v0.w, v1.x, v1.y, v1.z, v1.w};
    union { unsigned short u[8]; uint4 q; } hi, lo;
    #pragma unroll
    for (int j = 0; j < 8; ++j) {
        unsigned short h = bf16hi(vv[j]);
        hi.u[j] = h;
        lo.u[j] = bf16hi(vv[j] - bf16tof(h));
    }
    size_t tb = (size_t)gw * 1024;               // shorts
    *(uint4*)(Apk + tb + lane * 8)       = hi.q;
    *(uint4*)(Apk + tb + 512 + lane * 8) = lo.q;
}

// ---------------------------------------------------------------------------
// gemm_split2: A staged via global_load_lds from pre-converted Apk, AND the
// block's 16 KB B-slice staged to LDS once per K-step (was: each of 4 waves
// re-read the identical B fragments from global every kt -> 1.6 GB redundant
// L2 traffic in layer 0). MFMA loop reads A and B via conflict-free
// ds_read_b128. XCD-grouped bijective block swizzle for A-panel L2 reuse.
// ---------------------------------------------------------------------------
__global__ __launch_bounds__(256) void gemm_split2(
    const unsigned short* __restrict__ Apk, int M, int K,
    const unsigned short* __restrict__ Bf,   // [2][KT][32][64][8]
    const float* __restrict__ bl, const float* __restrict__ br,
    float* __restrict__ C)
{
    __shared__ unsigned short Af[2][8][64][8];   // 16 KB A (hi/lo x 8 mtiles)
    __shared__ unsigned short Bs[2][8][64][8];   // 16 KB B (hi/lo x 8 ntiles)
    const int tid  = threadIdx.x;
    const int lane = tid & 63;
    const int w    = tid >> 6;

    const int nwg = gridDim.x;
    const int q8 = nwg >> 3, r8 = nwg & 7;
    const int xcd = blockIdx.x & 7, idx = blockIdx.x >> 3;
    const int L = (xcd < r8) ? xcd * (q8 + 1) + idx
                             : r8 * (q8 + 1) + (xcd - r8) * q8 + idx;
    const int m0   = (L >> 2) * 128;
    const int n0   = (L & 3) * 128;
    const int KT   = K >> 5;
    const int ntg0 = n0 >> 4;
    const int mtg0 = m0 >> 4;

    f32x4 acc[2][8];
    #pragma unroll
    for (int i = 0; i < 2; ++i)
        #pragma unroll
        for (int j = 0; j < 8; ++j) acc[i][j] = (f32x4){0.f, 0.f, 0.f, 0.f};

    const size_t partStride = (size_t)KT * 32 * 512;   // shorts

    for (int kt = 0; kt < KT; ++kt) {
        // ---- stage A: 16 tiles (8 mt x 2 parts), 4 issues/wave ----
        #pragma unroll
        for (int ii = 0; ii < 4; ++ii) {
            int i = w * 4 + ii;
            int mt = i >> 1, part = i & 1;
            const unsigned short* g =
                Apk + ((size_t)((mtg0 + mt) * KT + kt) * 2 + part) * 512 + lane * 8;
            unsigned short* l = &Af[part][mt][0][0];
            __builtin_amdgcn_global_load_lds(
                (const __attribute__((address_space(1))) unsigned int*)g,
                (__attribute__((address_space(3))) unsigned int*)l, 16, 0, 0);
        }
        // ---- stage B: 16 tiles (8 nt x 2 parts), 4 issues/wave ----
        #pragma unroll
        for (int ii = 0; ii < 4; ++ii) {
            int j = w * 4 + ii;
            int part = j >> 3, nt = j & 7;
            const unsigned short* g =
                Bf + (size_t)part * partStride
                   + ((size_t)(kt * 32 + ntg0 + nt)) * 512 + lane * 8;
            unsigned short* l = &Bs[part][nt][0][0];
            __builtin_amdgcn_global_load_lds(
                (const __attribute__((address_space(1))) unsigned int*)g,
                (__attribute__((address_space(3))) unsigned int*)l, 16, 0, 0);
        }
        __syncthreads();

        bf16x8 ah0 = *(const bf16x8*)&Af[0][w * 2 + 0][lane][0];
        bf16x8 ah1 = *(const bf16x8*)&Af[0][w * 2 + 1][lane][0];
        bf16x8 al0 = *(const bf16x8*)&Af[1][w * 2 + 0][lane][0];
        bf16x8 al1 = *(const bf16x8*)&Af[1][w * 2 + 1][lane][0];

        #pragma unroll
        for (int nt = 0; nt < 8; ++nt) {
            bf16x8 bh  = *(const bf16x8*)&Bs[0][nt][lane][0];
            bf16x8 blv = *(const bf16x8*)&Bs[1][nt][lane][0];
            acc[0][nt] = __builtin_amdgcn_mfma_f32_16x16x32_bf16(ah0, bh,  acc[0][nt], 0, 0, 0);
            acc[1][nt] = __builtin_amdgcn_mfma_f32_16x16x32_bf16(ah1, bh,  acc[1][nt], 0, 0, 0);
            acc[0][nt] = __builtin_amdgcn_mfma_f32_16x16x32_bf16(ah0, blv, acc[0][nt], 0, 0, 0);
            acc[1][nt] = __builtin_amdgcn_mfma_f32_16x16x32_bf16(ah1, blv, acc[1][nt], 0, 0, 0);
            acc[0][nt] = __builtin_amdgcn_mfma_f32_16x16x32_bf16(al0, bh,  acc[0][nt], 0, 0, 0);
            acc[1][nt] = __builtin_amdgcn_mfma_f32_16x16x32_bf16(al1, bh,  acc[1][nt], 0, 0, 0);
        }
        __syncthreads();
    }

    const int q  = lane >> 4;
    const int cl = lane & 15;
    #pragma unroll
    for (int mti = 0; mti < 2; ++mti) {
        int gmb = m0 + (w * 2 + mti) * 16 + q * 4;
        #pragma unroll
        for (int nt = 0; nt < 8; ++nt) {
            int col = n0 + nt * 16 + cl;
            float bia = (col < 256) ? bl[col] : br[col - 256];
            #pragma unroll
            for (int r = 0; r < 4; ++r) {
                int gm = gmb + r;
                if (gm < M) C[(size_t)gm * 512 + col] = acc[mti][nt][r] + bia;
            }
        }
    }
}

// ---------------------------------------------------------------------------
// gemm_split (fallback): in-loop fp32->bf16 staging.
// ---------------------------------------------------------------------------
__global__ __launch_bounds__(256) void gemm_split(
    const float* __restrict__ A, int M, int K,
    const unsigned short* __restrict__ Bf,
    const float* __restrict__ bl, const float* __restrict__ br,
    float* __restrict__ C)
{
    __shared__ unsigned short Af[2][8][64][8];
    const int tid  = threadIdx.x;
    const int lane = tid & 63;
    const int w    = tid >> 6;
    const int m0   = blockIdx.x * 128;
    const int n0   = blockIdx.y * 128;
    const int KT   = K >> 5;
    const int ntg0 = n0 >> 4;

    f32x4 acc[2][8];
    #pragma unroll
    for (int i = 0; i < 2; ++i)
        #pragma unroll
        for (int j = 0; j < 8; ++j) acc[i][j] = (f32x4){0.f, 0.f, 0.f, 0.f};

    const size_t partStride = (size_t)KT * 32 * 512;

    for (int kt = 0; kt < KT; ++kt) {
        #pragma unroll
        for (int i = 0; i < 4; ++i) {
            int idx = tid * 4 + i;
            int r   = idx >> 3;
            int kl  = (idx & 7) * 4;
            int gm  = m0 + r;
            float4 v = make_float4(0.f, 0.f, 0.f, 0.f);
            if (gm < M) v = *(const float4*)(A + (size_t)gm * K + kt * 32 + kl);
            unsigned short h0 = bf16hi(v.x), h1 = bf16hi(v.y);
            unsigned short h2 = bf16hi(v.z), h3 = bf16hi(v.w);
            unsigned short l0 = bf16hi(v.x - bf16tof(h0));
            unsigned short l1 = bf16hi(v.y - bf16tof(h1));
            unsigned short l2 = bf16hi(v.z - bf16tof(h2));
            unsigned short l3 = bf16hi(v.w - bf16tof(h3));
            int mt = r >> 4;
            int la = (r & 15) | ((kl >> 3) << 4);
            int j0 = kl & 7;
            *(uint2*)&Af[0][mt][la][j0] =
                make_uint2((unsigned int)h0 | ((unsigned int)h1 << 16),
                           (unsigned int)h2 | ((unsigned int)h3 << 16));
            *(uint2*)&Af[1][mt][la][j0] =
                make_uint2((unsigned int)l0 | ((unsigned int)l1 << 16),
                           (unsigned int)l2 | ((unsigned int)l3 << 16));
        }
        __syncthreads();

        bf16x8 ah0 = *(const bf16x8*)&Af[0][w * 2 + 0][lane][0];
        bf16x8 ah1 = *(const bf16x8*)&Af[0][w * 2 + 1][lane][0];
        bf16x8 al0 = *(const bf16x8*)&Af[1][w * 2 + 0][lane][0];
        bf16x8 al1 = *(const bf16x8*)&Af[1][w * 2 + 1][lane][0];

        const unsigned short* bbase =
            Bf + ((size_t)kt * 32 + ntg0) * 512 + (size_t)lane * 8;
        #pragma unroll
        for (int nt = 0; nt < 8; ++nt) {
            bf16x8 bh  = *(const bf16x8*)(bbase + (size_t)nt * 512);
            bf16x8 blv = *(const bf16x8*)(bbase + partStride + (size_t)nt * 512);
            acc[0][nt] = __builtin_amdgcn_mfma_f32_16x16x32_bf16(ah0, bh,  acc[0][nt], 0, 0, 0);
            acc[1][nt] = __builtin_amdgcn_mfma_f32_16x16x32_bf16(ah1, bh,  acc[1][nt], 0, 0, 0);
            acc[0][nt] = __builtin_amdgcn_mfma_f32_16x16x32_bf16(ah0, blv, acc[0][nt], 0, 0, 0);
            acc[1][nt] = __builtin_amdgcn_mfma_f32_16x16x32_bf16(ah1, blv, acc[1][nt], 0, 0, 0);
            acc[0][nt] = __builtin_amdgcn_mfma_f32_16x16x32_bf16(al0, bh,  acc[0][nt], 0, 0, 0);
            acc[1][nt] = __builtin_amdgcn_mfma_f32_16x16x32_bf16(al1, bh,  acc[1][nt], 0, 0, 0);
        }
        __syncthreads();
    }

    const int q  = lane >> 4;
    const int cl = lane & 15;
    #pragma unroll
    for (int mti = 0; mti < 2; ++mti) {
        int gmb = m0 + (w * 2 + mti) * 16 + q * 4;
        #pragma unroll
        for (int nt = 0; nt < 8; ++nt) {
            int col = n0 + nt * 16 + cl;
            float bia = (col < 256) ? bl[col] : br[col - 256];
            #pragma unroll
            for (int r = 0; r < 4; ++r) {
                int gm = gmb + r;
                if (gm < M) C[(size_t)gm * 512 + col] = acc[mti][nt][r] + bia;
            }
        }
    }
}

// ---------------------------------------------------------------------------
// FUSED logit + aggregate (unchanged — at scatter-BW ceiling).
// ---------------------------------------------------------------------------
template<bool PROJ>
__global__ __launch_bounds__(256) void gat_fused_t(
    const float* __restrict__ xlxr,
    const float* __restrict__ edge_attr,
    const int* __restrict__ col_src,
    const int* __restrict__ col_dst,
    const int* __restrict__ col_eid,
    const int* __restrict__ row_ptr,
    const unsigned short* __restrict__ WePl,
    const float* __restrict__ att,
    const float* __restrict__ bias,
    float* __restrict__ nmr,
    const float* __restrict__ Wout,
    const float* __restrict__ bout,
    float* __restrict__ out,
    float* __restrict__ denomB,
    int E, int W)
{
    __shared__ unsigned short AhiS[16][64][8];
    __shared__ unsigned short AloS[16][64][8];
    const int tid = threadIdx.x;
    #pragma unroll
    for (int i = 0; i < 4; ++i) {
        int idx = tid * 4 + i;
        ((uint4*)&AhiS[0][0][0])[idx] = ((const uint4*)WePl)[idx];
        ((uint4*)&AloS[0][0][0])[idx] = ((const uint4*)(WePl + 8192))[idx];
    }
    __syncthreads();

    const int lane  = tid & 63;
    const int wid   = tid >> 6;
    const int q     = lane >> 4;
    const int e_sub = lane & 15;
    const int kb    = q * 8;
    const int ch4   = lane * 4;

    const int gw = blockIdx.x * 4 + wid;
    const int s_range = gw * W;
    if (s_range >= E) return;
    const int eEnd = min(E, s_range + W);

    const float4 bia4 = *(const float4*)(bias + ch4);
    float4 wo4 = make_float4(0.f, 0.f, 0.f, 0.f);
    if (PROJ) wo4 = *(const float4*)(Wout + ch4);

    int curDst = -1;
    float4 accB = make_float4(0.f, 0.f, 0.f, 0.f);
    float denB = 0.f;

    auto flush = [&]() {
        if (curDst >= 0) {
            int ra = row_ptr[curDst], rb = row_ptr[curDst + 1];
            bool comp = (ra % W != 0) && (rb % W != 0) && (ra / W == (rb - 1) / W);
            if (comp) {
                float inv = 1.0f / denB;
                float4 o;
                o.x = fmaxf(fmaf(accB.x, inv, bia4.x), 0.f);
                o.y = fmaxf(fmaf(accB.y, inv, bia4.y), 0.f);
                o.z = fmaxf(fmaf(accB.z, inv, bia4.z), 0.f);
                o.w = fmaxf(fmaf(accB.w, inv, bia4.w), 0.f);
                if (!PROJ) {
                    *(float4*)(nmr + (size_t)curDst * 256 + ch4) = o;
                } else {
                    float s = o.x * wo4.x;
                    s = fmaf(o.y, wo4.y, s);
                    s = fmaf(o.z, wo4.z, s);
                    s = fmaf(o.w, wo4.w, s);
                    #pragma unroll
                    for (int off = 32; off > 0; off >>= 1)
                        s += __shfl_xor(s, off, 64);
                    if (lane == 0) out[curDst] = s + bout[0];
                }
            } else {
                float* np = nmr + (size_t)curDst * 256 + ch4;
                atomicAdd(np + 0, accB.x);
                atomicAdd(np + 1, accB.y);
                atomicAdd(np + 2, accB.z);
                atomicAdd(np + 3, accB.w);
                if (e_sub == 0) atomicAdd(denomB + curDst * 4 + q, denB);
            }
            accB = make_float4(0.f, 0.f, 0.f, 0.f);
            denB = 0.f;
        }
    };

    for (int base = s_range; base < eEnd; base += 16) {
        const int cnt  = min(16, eEnd - base);
        const int slot = base + e_sub;
        const int sc   = min(slot, eEnd - 1);
        const int eid  = col_eid[sc];
        const int srcn = col_src[sc];
        const int dstn = col_dst[sc];

        const float* ap = edge_attr + (size_t)eid * 32 + kb;
        float4 v0 = *(const float4*)ap;
        float4 v1 = *(const float4*)(ap + 4);
        float vv[8] = {v0.x, v0.y, v0.z, v0.w, v1.x, v1.y, v1.z, v1.w};
        union { bf16x8 v; unsigned short u[8]; } bh, bl;
        #pragma unroll
        for (int i = 0; i < 8; ++i) {
            unsigned short hh = bf16hi(vv[i]);
            bh.u[i] = hh;
            bl.u[i] = bf16hi(vv[i] - bf16tof(hh));
        }

        const float* xlp = xlxr + (size_t)srcn * 512 + q * 4;
        const float* xrp = xlxr + (size_t)dstn * 512 + 256 + q * 4;

        float lph[4] = {0.f, 0.f, 0.f, 0.f};
        #pragma unroll
        for (int t = 0; t < 16; ++t) {
            bf16x8 ahi = *(const bf16x8*)&AhiS[t][lane][0];
            bf16x8 alo = *(const bf16x8*)&AloS[t][lane][0];
            f32x4 macc = {0.f, 0.f, 0.f, 0.f};
            macc = __builtin_amdgcn_mfma_f32_16x16x32_bf16(ahi, bh.v, macc, 0, 0, 0);
            macc = __builtin_amdgcn_mfma_f32_16x16x32_bf16(ahi, bl.v, macc, 0, 0, 0);
            macc = __builtin_amdgcn_mfma_f32_16x16x32_bf16(alo, bh.v, macc, 0, 0, 0);
            const float4 xl4 = *(const float4*)(xlp + t * 16);
            const float4 xr4 = *(const float4*)(xrp + t * 16);
            const float4 at4 = *(const float4*)(att + t * 16 + q * 4);
            float z0 = macc[0] + xl4.x + xr4.x; z0 = (z0 > 0.f) ? z0 : NEG_SLOPE * z0;
            float z1 = macc[1] + xl4.y + xr4.y; z1 = (z1 > 0.f) ? z1 : NEG_SLOPE * z1;
            float z2 = macc[2] + xl4.z + xr4.z; z2 = (z2 > 0.f) ? z2 : NEG_SLOPE * z2;
            float z3 = macc[3] + xl4.w + xr4.w; z3 = (z3 > 0.f) ? z3 : NEG_SLOPE * z3;
            float s = z0 * at4.x;
            s = fmaf(z1, at4.y, s);
            s = fmaf(z2, at4.z, s);
            s = fmaf(z3, at4.w, s);
            lph[t >> 2] += s;
        }
        #pragma unroll
        for (int hh = 0; hh < 4; ++hh) {
            lph[hh] += __shfl_xor(lph[hh], 16, 64);
            lph[hh] += __shfl_xor(lph[hh], 32, 64);
        }
        float lsel = (q == 0) ? lph[0] : (q == 1) ? lph[1] : (q == 2) ? lph[2] : lph[3];
        float psrc = __expf(lsel);

        auto phaseB = [&](int cnt2) {
            for (int eb = 0; eb < cnt2; eb += 4) {
                float pv[4]; int sv[4], dv[4];
                #pragma unroll
                for (int i = 0; i < 4; ++i) {
                    int e = eb + i;
                    int ec = (e < cnt2) ? e : cnt2 - 1;
                    pv[i] = __shfl(psrc, (lane & 48) | ec, 64);
                    if (e >= cnt2) pv[i] = 0.f;
                    sv[i] = __shfl(srcn, ec, 64);
                    dv[i] = __shfl(dstn, ec, 64);
                }
                float4 xv[4];
                #pragma unroll
                for (int i = 0; i < 4; ++i)
                    xv[i] = *(const float4*)(xlxr + (size_t)sv[i] * 512 + ch4);
                #pragma unroll
                for (int i = 0; i < 4; ++i) {
                    if (dv[i] != curDst) { flush(); curDst = dv[i]; }
                    denB += pv[i];
                    accB.x = fmaf(pv[i], xv[i].x, accB.x);
                    accB.y = fmaf(pv[i], xv[i].y, accB.y);
                    accB.z = fmaf(pv[i], xv[i].z, accB.z);
                    accB.w = fmaf(pv[i], xv[i].w, accB.w);
                }
            }
        };
        if (cnt == 16) phaseB(16); else phaseB(cnt);
    }
    flush();
}

// ---------------------------------------------------------------------------
// Finalize: boundary-run + deg-0 nodes (unchanged).
// ---------------------------------------------------------------------------
template<bool PROJ>
__global__ __launch_bounds__(256) void finalize_t(
    const int* __restrict__ row_ptr,
    const float* __restrict__ denomB,
    const float* __restrict__ bias,
    float* __restrict__ nmr,
    const float* __restrict__ Wout, const float* __restrict__ bout,
    float* __restrict__ out, int N, int W)
{
    const int tid  = threadIdx.x;
    const int lane = tid & 63;
    const int wid  = tid >> 6;
    const int n = blockIdx.x * 4 + wid;
    if (n >= N) return;
    const int q   = lane >> 4;
    const int ch4 = lane * 4;

    const int a = row_ptr[n], b = row_ptr[n + 1];
    float4 o;
    if (a == b) {
        const float4 bia = *(const float4*)(bias + ch4);
        o.x = fmaxf(bia.x, 0.f);
        o.y = fmaxf(bia.y, 0.f);
        o.z = fmaxf(bia.z, 0.f);
        o.w = fmaxf(bia.w, 0.f);
    } else {
        bool comp = (a % W != 0) && (b % W != 0) && (a / W == (b - 1) / W);
        if (comp) return;
        const float4 nm = *(const float4*)(nmr + (size_t)n * 256 + ch4);
        const float inv = 1.0f / denomB[n * 4 + q];
        const float4 bia = *(const float4*)(bias + ch4);
        o.x = fmaxf(fmaf(nm.x, inv, bia.x), 0.f);
        o.y = fmaxf(fmaf(nm.y, inv, bia.y), 0.f);
        o.z = fmaxf(fmaf(nm.z, inv, bia.z), 0.f);
        o.w = fmaxf(fmaf(nm.w, inv, bia.w), 0.f);
    }
    if (!PROJ) {
        *(float4*)(nmr + (size_t)n * 256 + ch4) = o;
    } else {
        const float4 w4 = *(const float4*)(Wout + ch4);
        float s = o.x * w4.x;
        s = fmaf(o.y, w4.y, s);
        s = fmaf(o.z, w4.z, s);
        s = fmaf(o.w, w4.w, s);
        #pragma unroll
        for (int off = 32; off > 0; off >>= 1)
            s += __shfl_xor(s, off, 64);
        if (lane == 0) out[n] = s + bout[0];
    }
}

// ---------------------------------------------------------------------------
extern "C" void kernel_launch(void* const* d_in, const int* in_sizes, int n_in,
                              void* d_out, int out_size, void* d_ws, size_t ws_size,
                              hipStream_t stream) {
    const float* x         = (const float*)d_in[0];
    const int*   edge_idx  = (const int*)d_in[1];
    const float* edge_attr = (const float*)d_in[2];
    const float* W_l0 = (const float*)d_in[3];
    const float* b_l0 = (const float*)d_in[4];
    const float* W_r0 = (const float*)d_in[5];
    const float* b_r0 = (const float*)d_in[6];
    const float* W_e0 = (const float*)d_in[7];
    const float* att0 = (const float*)d_in[8];
    const float* bias0= (const float*)d_in[9];
    const float* W_l1 = (const float*)d_in[10];
    const float* b_l1 = (const float*)d_in[11];
    const float* W_r1 = (const float*)d_in[12];
    const float* b_r1 = (const float*)d_in[13];
    const float* W_e1 = (const float*)d_in[14];
    const float* att1 = (const float*)d_in[15];
    const float* bias1= (const float*)d_in[16];
    const float* W_out= (const float*)d_in[17];
    const float* b_out= (const float*)d_in[18];

    const int N = in_sizes[0] / 512;      // 50000
    const int E = in_sizes[1] / 2;        // 800000

    const int* src = edge_idx;
    const int* dst = edge_idx + E;

    // workspace layout
    char* ws = (char*)d_ws;
    size_t off = 0;
    float* bufA   = (float*)(ws + off); off += (size_t)N * 512 * 4;   // 102.4 MB
    float* bufB   = (float*)(ws + off); off += (size_t)N * 256 * 4;   //  51.2 MB
    float* denomB = (float*)(ws + off); off += (size_t)N * 4 * 4;     //   0.8 MB
    int* row_ptr  = (int*)(ws + off);   off += (((size_t)(N + 1) * 4 + 255) & ~(size_t)255);
    int* cursor   = (int*)(ws + off);   off += (((size_t)N * 4 + 255) & ~(size_t)255);
    int* col_src  = (int*)(ws + off);   off += (size_t)E * 4;
    int* col_dst  = (int*)(ws + off);   off += (size_t)E * 4;
    int* col_eid  = (int*)(ws + off);   off += (size_t)E * 4;
    int* totals   = (int*)(ws + off);   off += 1024;
    unsigned short* WeP = (unsigned short*)(ws + off); off += 4096 * 8 * 2;        // 64 KB
    unsigned short* Bf0 = (unsigned short*)(ws + off); off += (size_t)2 * 16 * 32 * 64 * 8 * 2; // 1 MB
    unsigned short* Bf1 = (unsigned short*)(ws + off); off += (size_t)2 * 8 * 32 * 64 * 8 * 2;  // 512 KB

    // Apk: shared region for pre-converted A (layer0: [M,512], layer1: [M,256])
    const int ntiles0 = (N >> 4) * 16;     // (M/16)*(512/32)
    const int ntiles1 = (N >> 4) * 8;      // (M/16)*(256/32)
    unsigned short* Apk = (unsigned short*)(ws + off);
    size_t apkBytes = (size_t)(ntiles0 > ntiles1 ? ntiles0 : ntiles1) * 2048 + 131072;
    off += apkBytes;
    const bool fast = (off <= ws_size) && ((N & 15) == 0);

    const int nbE = (E + 255) / 256;
    const int nbN = (N + 255) / 256;

    // ---- CSR build + weight prepack ----
    hipMemsetAsync(cursor, 0, (size_t)N * 4, stream);
    hist_kernel<<<nbE, 256, 0, stream>>>(dst, cursor, E);
    scan_s1<<<nbN, 256, 0, stream>>>(cursor, row_ptr, totals, N);
    scan_s2<<<1, 256, 0, stream>>>(totals, nbN);
    scan_s3<<<nbN, 256, 0, stream>>>(row_ptr, totals, cursor, N, E);
    scatter_kernel<<<nbE, 256, 0, stream>>>(src, dst, cursor, col_src, col_dst, col_eid, E);
    pack_we<<<16, 256, 0, stream>>>(W_e0, W_e1, WeP);
    pack_w<<<256, 256, 0, stream>>>(W_l0, W_r0, 16, Bf0);
    pack_w<<<128, 256, 0, stream>>>(W_l1, W_r1, 8, Bf1);

    const int nbx = (N + 127) / 128;
    dim3 ggrid(nbx, 4);

    // fused-kernel geometry
    const int NW  = 8192;
    const int nch = (E + 15) / 16;
    const int C   = (nch + NW - 1) / NW;
    const int W   = C * 16;
    const int nfin = (N + 3) / 4;

    // ---- Layer 0 ----
    if (fast) {
        conv_a<<<(ntiles0 + 3) / 4, 256, 0, stream>>>(x, 512, ntiles0, Apk);
        gemm_split2<<<nbx * 4, 256, 0, stream>>>(Apk, N, 512, Bf0, b_l0, b_r0, bufA);
    } else {
        gemm_split<<<ggrid, 256, 0, stream>>>(x, N, 512, Bf0, b_l0, b_r0, bufA);
    }
    hipMemsetAsync(bufB,   0, (size_t)N * 256 * 4, stream);
    hipMemsetAsync(denomB, 0, (size_t)N * 4 * 4,   stream);
    gat_fused_t<false><<<2048, 256, 0, stream>>>(
        bufA, edge_attr, col_src, col_dst, col_eid, row_ptr, WeP, att0, bias0,
        bufB, nullptr, nullptr, nullptr, denomB, E, W);
    finalize_t<false><<<nfin, 256, 0, stream>>>(
        row_ptr, denomB, bias0, bufB, nullptr, nullptr, nullptr, N, W);

    // ---- Layer 1 ----
    if (fast) {
        conv_a<<<(ntiles1 + 3) / 4, 256, 0, stream>>>(bufB, 256, ntiles1, Apk);
        gemm_split2<<<nbx * 4, 256, 0, stream>>>(Apk, N, 256, Bf1, b_l1, b_r1, bufA);
    } else {
        gemm_split<<<ggrid, 256, 0, stream>>>(bufB, N, 256, Bf1, b_l1, b_r1, bufA);
    }
    hipMemsetAsync(bufB,   0, (size_t)N * 256 * 4, stream);
    hipMemsetAsync(denomB, 0, (size_t)N * 4 * 4,   stream);
    gat_fused_t<true><<<2048, 256, 0, stream>>>(
        bufA, edge_attr, col_src, col_dst, col_eid, row_ptr, WeP + 16384, att1, bias1,
        bufB, W_out, b_out, (float*)d_out, denomB, E, W);
    finalize_t<true><<<nfin, 256, 0, stream>>>(
        row_ptr, denomB, bias1, bufB, W_out, b_out, (float*)d_out, N, W);
}